// Round 3
// baseline (588.854 us; speedup 1.0000x reference)
//
#include <hip/hip_runtime.h>
#include <math.h>

#define LSEQ 2048
#define NB 2
#define HDIM 1024
#define NKV 128          // 2*HEAD_SIZE
#define MALL (NB*LSEQ)   // 4096
#define KSPLIT 4

typedef float vf4 __attribute__((ext_vector_type(4)));  // native vector: NT-storable

// ---------------- K1: seq_out partials = inputs @ Wp (K split in 4) --------
// grid (8, 64): x = nt(2) + 2*split(4), y = m-tile. 256 threads, 64x64 tile,
// micro 4x4 per thread, K-chunk 32, 8 chunks per split.
__global__ __launch_bounds__(256) void k1_gemm(const float* __restrict__ A,
                                               const float* __restrict__ Wp,
                                               float* __restrict__ Cp) {
    const int nt    = blockIdx.x & 1;
    const int split = blockIdx.x >> 1;
    const int m0 = blockIdx.y * 64;
    const int n0 = nt * 64;
    __shared__ float As[32][68];   // [k][m], pad 68 keeps float4 reads 16B-aligned
    __shared__ float Bs[32][64];   // [k][n]
    const int tid = threadIdx.x;
    const int tm = tid & 15;       // m quad
    const int tn = tid >> 4;       // n quad
    float acc[4][4] = {};
    for (int kc = 0; kc < 8; ++kc) {
        const int k0 = split*256 + kc*32;
        #pragma unroll
        for (int p = 0; p < 2; ++p) {
            int idx = tid + 256*p;          // 0..511
            int row = idx >> 3, kq = idx & 7;
            float4 a = *(const float4*)(A + (size_t)(m0+row)*HDIM + k0 + 4*kq);
            As[4*kq+0][row] = a.x;
            As[4*kq+1][row] = a.y;
            As[4*kq+2][row] = a.z;
            As[4*kq+3][row] = a.w;
        }
        #pragma unroll
        for (int p = 0; p < 2; ++p) {
            int idx = tid + 256*p;
            int r = idx >> 4, c = idx & 15;
            *(float4*)(&Bs[r][4*c]) = *(const float4*)(Wp + (size_t)(k0+r)*NKV + n0 + 4*c);
        }
        __syncthreads();
        #pragma unroll
        for (int kk = 0; kk < 32; ++kk) {
            float4 av = *(const float4*)(&As[kk][4*tm]);
            float4 bv = *(const float4*)(&Bs[kk][4*tn]);
            float aa[4] = {av.x, av.y, av.z, av.w};
            float bb[4] = {bv.x, bv.y, bv.z, bv.w};
            #pragma unroll
            for (int i = 0; i < 4; ++i)
                #pragma unroll
                for (int j = 0; j < 4; ++j)
                    acc[i][j] = fmaf(aa[i], bb[j], acc[i][j]);
        }
        __syncthreads();
    }
    float* outp = Cp + (size_t)split*MALL*NKV;
    #pragma unroll
    for (int i = 0; i < 4; ++i) {
        float4 v = make_float4(acc[i][0], acc[i][1], acc[i][2], acc[i][3]);
        *(float4*)(outp + (size_t)(m0 + 4*tm + i)*NKV + n0 + 4*tn) = v;
    }
}

// ---------------- K2: sum K-splits (+bp), RoPE, bias = seq@Wq/2 ------------
// grid 4096 blocks x 64 threads (1 wave per row).
__global__ __launch_bounds__(64) void k2_rope_bias(const float* __restrict__ Cp,
        const float* __restrict__ bp, const float* __restrict__ Wq,
        const float* __restrict__ bq, float* __restrict__ qwout,
        float* __restrict__ kwout, float* __restrict__ biasQ,
        float* __restrict__ biasK) {
    const int row = blockIdx.x;         // 0..4095 (b*L + l)
    const int b = row >> 11;
    const int l = row & (LSEQ - 1);
    const int t = threadIdx.x;          // 0..63 ; lane t owns dims (2t, 2t+1)
    float x0 = bp[2*t], x1 = bp[2*t+1];
    #pragma unroll
    for (int s = 0; s < KSPLIT; ++s) {
        const float* r = Cp + (size_t)s*MALL*NKV + (size_t)row*NKV;
        x0 += r[2*t];
        x1 += r[2*t+1];
    }
    // RoPE: lanes 0..31 -> q (dims 0..63), lanes 32..63 -> k (dims 64..127)
    const int p = t & 31;               // pair index within head
    float inv = exp2f(-0.41524101186098287f * (float)p);  // 10000^(-p/32)
    float ang = (float)l * inv;
    float sn = sinf(ang), cs = cosf(ang);
    float y0 = x0*cs - x1*sn;
    float y1 = x1*cs + x0*sn;
    float* dst = (t < 32) ? (qwout + (size_t)row*64) : (kwout + (size_t)row*64);
    dst[2*p]   = y0;
    dst[2*p+1] = y1;
    // bias: 24 dot-products of (pre-RoPE) row with Wq columns, wave-reduced
    float res = 0.f;
    for (int j = 0; j < 24; ++j) {
        float part = fmaf(x0, Wq[(2*t)*24 + j], x1 * Wq[(2*t+1)*24 + j]);
        #pragma unroll
        for (int off = 32; off > 0; off >>= 1)
            part += __shfl_xor(part, off);
        if (t == j) res = part;
    }
    if (t < 24) {
        float v = (res + bq[t]) * 0.5f;
        int h = t >> 1;
        float* bb = (t & 1) ? biasK : biasQ;
        bb[((size_t)b*12 + h)*LSEQ + l] = v;
    }
}

// ---------------- K3: raw scores -> out[b][head0] region (L3-resident) -----
// grid (256, 2): x = m-tile (8 rows), y = b. 256 threads = 4 waves.
// Wave w owns rows m0+2w, m0+2w+1 (q in 128 VGPRs, read-shared across both
// rows). n in 8 chunks of 256; kw chunk staged in 64 KB LDS, XOR-swizzled
// quads -> conflict-free ds_read_b128. Lane l owns n-quad 4l..4l+3.
// Writes RAW scores (scaled 1/8) as plain float4 stores: 33.5 MB per b pair,
// deliberately cached so K4's 12 re-reads are L3 hits.
__global__ __launch_bounds__(256, 2) void k3_scores(const float* __restrict__ qw,
        const float* __restrict__ kwv, float* __restrict__ out) {
    extern __shared__ float kws[];          // 256*64 floats = 64 KB
    const int m0  = blockIdx.x * 8;
    const int b   = blockIdx.y;
    const int tid = threadIdx.x;
    const int w   = tid >> 6;               // wave -> row pair
    const int l   = tid & 63;               // lane -> n quad
    const int swz = l & 7;
    const size_t rowbase = (size_t)b * LSEQ;
    const int mA = m0 + 2*w, mB = mA + 1;

    float4 qa[16], qb[16];
    {
        const float4* pa = (const float4*)(qw + (rowbase + mA)*64);
        const float4* pb = (const float4*)(qw + (rowbase + mB)*64);
        #pragma unroll
        for (int j = 0; j < 16; ++j) { qa[j] = pa[j]; qb[j] = pb[j]; }
    }
    float* S = out + (size_t)b*12*LSEQ*LSEQ;   // head-0 region holds raw scores

    for (int s = 0; s < 8; ++s) {
        __syncthreads();                    // protect kws from prev chunk readers
        #pragma unroll
        for (int p = 0; p < 16; ++p) {
            int F = tid + 256*p;            // float4 index in 256x64 chunk
            int r = F >> 4, qd = F & 15;
            float4 v = *(const float4*)(kwv + (rowbase + s*256 + r)*64 + 4*qd);
            *(float4*)(&kws[r*64 + 4*(qd ^ ((r>>2)&7))]) = v;
        }
        __syncthreads();

        float a0=0.f,a1=0.f,a2=0.f,a3=0.f;
        float c0=0.f,c1=0.f,c2=0.f,c3=0.f;
        const float* kb = kws + 256*l;      // rows 4l..4l+3
        #pragma unroll
        for (int j = 0; j < 16; ++j) {
            const int qo = 4*(j ^ swz);
            float4 k0 = *(const float4*)(kb + qo);
            float4 k1 = *(const float4*)(kb + 64 + qo);
            float4 k2 = *(const float4*)(kb + 128 + qo);
            float4 k3 = *(const float4*)(kb + 192 + qo);
            float4 qv = qa[j];
            a0 = fmaf(qv.x,k0.x,fmaf(qv.y,k0.y,fmaf(qv.z,k0.z,fmaf(qv.w,k0.w,a0))));
            a1 = fmaf(qv.x,k1.x,fmaf(qv.y,k1.y,fmaf(qv.z,k1.z,fmaf(qv.w,k1.w,a1))));
            a2 = fmaf(qv.x,k2.x,fmaf(qv.y,k2.y,fmaf(qv.z,k2.z,fmaf(qv.w,k2.w,a2))));
            a3 = fmaf(qv.x,k3.x,fmaf(qv.y,k3.y,fmaf(qv.z,k3.z,fmaf(qv.w,k3.w,a3))));
            qv = qb[j];
            c0 = fmaf(qv.x,k0.x,fmaf(qv.y,k0.y,fmaf(qv.z,k0.z,fmaf(qv.w,k0.w,c0))));
            c1 = fmaf(qv.x,k1.x,fmaf(qv.y,k1.y,fmaf(qv.z,k1.z,fmaf(qv.w,k1.w,c1))));
            c2 = fmaf(qv.x,k2.x,fmaf(qv.y,k2.y,fmaf(qv.z,k2.z,fmaf(qv.w,k2.w,c2))));
            c3 = fmaf(qv.x,k3.x,fmaf(qv.y,k3.y,fmaf(qv.z,k3.z,fmaf(qv.w,k3.w,c3))));
        }
        const int nq = s*256 + 4*l;
        float4 va = make_float4(a0*0.125f, a1*0.125f, a2*0.125f, a3*0.125f);
        float4 vb = make_float4(c0*0.125f, c1*0.125f, c2*0.125f, c3*0.125f);
        *(float4*)(S + (size_t)mA*LSEQ + nq) = va;
        *(float4*)(S + (size_t)mB*LSEQ + nq) = vb;
    }
}

// ---------------- K4: fan-out -> fill-style contiguous NT streams ----------
// pass 0: grid (128, 22) -> (b, h=1..11). Each block owns out[b][h][m0..m0+15][:]
//   = one CONTIGUOUS 128 KB ascending stream (the fillBuffer-proven pattern).
//   Reads raw scores from out[b][0] (L3 hit) + biases, NT-stores result.
// pass 1: grid (128, 2) -> h=0: finalize score region IN PLACE (separate
//   dispatch so pass-0 readers of the raw scores are already done).
__global__ __launch_bounds__(256) void k4_fanout(const float* __restrict__ biasQ,
        const float* __restrict__ biasK, const int* __restrict__ mask,
        float* __restrict__ out, int pass) {
    int b, h;
    if (pass == 0) { b = blockIdx.y / 11; h = 1 + blockIdx.y % 11; }
    else           { b = blockIdx.y;      h = 0; }
    const int m0  = blockIdx.x * 16;
    const int tid = threadIdx.x;
    const size_t rowb = (size_t)b * LSEQ;
    const float* S = out + (size_t)b*12*LSEQ*LSEQ;            // raw scores (h0)
    float* O = out + ((size_t)b*12 + h)*LSEQ*LSEQ;
    const int nA = 4*tid, nB = 4*tid + 1024;                  // two coalesced halves

    const float* bkp = biasK + ((size_t)b*12 + h)*LSEQ;
    const float4 bkA = *(const float4*)(bkp + nA);
    const float4 bkB = *(const float4*)(bkp + nB);
    const int4 mnA = *(const int4*)(mask + rowb + nA);
    const int4 mnB = *(const int4*)(mask + rowb + nB);
    const float* bqp = biasQ + ((size_t)b*12 + h)*LSEQ;

    #pragma unroll 4
    for (int r = 0; r < 16; ++r) {
        const int m = m0 + r;
        const float bq = bqp[m];
        const bool okm = mask[rowb + m] != 0;
        const float* srow = S + (size_t)m*LSEQ;
        float4 sA = *(const float4*)(srow + nA);
        float4 sB = *(const float4*)(srow + nB);
        vf4 vA, vB;
        vA.x = (okm && mnA.x) ? (sA.x + bq + bkA.x) - ((m > nA+0) ? 1e12f : 0.f) : -INFINITY;
        vA.y = (okm && mnA.y) ? (sA.y + bq + bkA.y) - ((m > nA+1) ? 1e12f : 0.f) : -INFINITY;
        vA.z = (okm && mnA.z) ? (sA.z + bq + bkA.z) - ((m > nA+2) ? 1e12f : 0.f) : -INFINITY;
        vA.w = (okm && mnA.w) ? (sA.w + bq + bkA.w) - ((m > nA+3) ? 1e12f : 0.f) : -INFINITY;
        vB.x = (okm && mnB.x) ? (sB.x + bq + bkB.x) - ((m > nB+0) ? 1e12f : 0.f) : -INFINITY;
        vB.y = (okm && mnB.y) ? (sB.y + bq + bkB.y) - ((m > nB+1) ? 1e12f : 0.f) : -INFINITY;
        vB.z = (okm && mnB.z) ? (sB.z + bq + bkB.z) - ((m > nB+2) ? 1e12f : 0.f) : -INFINITY;
        vB.w = (okm && mnB.w) ? (sB.w + bq + bkB.w) - ((m > nB+3) ? 1e12f : 0.f) : -INFINITY;
        __builtin_nontemporal_store(vA, (vf4*)(O + (size_t)m*LSEQ + nA));
        __builtin_nontemporal_store(vB, (vf4*)(O + (size_t)m*LSEQ + nB));
    }
}

extern "C" void kernel_launch(void* const* d_in, const int* in_sizes, int n_in,
                              void* d_out, int out_size, void* d_ws, size_t ws_size,
                              hipStream_t stream) {
    const float* inputs = (const float*)d_in[0];   // (2,2048,1024)
    const int*   mask   = (const int*)  d_in[1];   // (2,2048)
    const float* Wp     = (const float*)d_in[2];   // (1024,128)
    const float* bp     = (const float*)d_in[3];   // (128,)
    const float* Wq     = (const float*)d_in[4];   // (128,24)
    const float* bq     = (const float*)d_in[5];   // (24,)
    float* out = (float*)d_out;                    // (2,12,2048,2048)

    float* Cp  = (float*)d_ws;                     // KSPLIT * 4096 * 128
    float* qwb = Cp  + (size_t)KSPLIT*MALL*NKV;    // 4096 * 64
    float* kwb = qwb + (size_t)MALL*64;            // 4096 * 64
    float* bQ  = kwb + (size_t)MALL*64;            // 2*12*2048
    float* bK  = bQ  + (size_t)NB*12*LSEQ;         // 2*12*2048

    k1_gemm     <<<dim3(8, 64),   256, 0, stream>>>(inputs, Wp, Cp);
    k2_rope_bias<<<dim3(MALL),     64, 0, stream>>>(Cp, bp, Wq, bq, qwb, kwb, bQ, bK);
    k3_scores   <<<dim3(256, 2), 256, 65536, stream>>>(qwb, kwb, out);
    k4_fanout   <<<dim3(128, 22), 256, 0, stream>>>(bQ, bK, mask, out, 0);
    k4_fanout   <<<dim3(128, 2),  256, 0, stream>>>(bQ, bK, mask, out, 1);
}

// Round 5
// 484.503 us; speedup vs baseline: 1.2154x; 1.2154x over previous
//
#include <hip/hip_runtime.h>
#include <math.h>

#define LSEQ 2048
#define NB 2
#define HDIM 1024
#define NKV 128          // 2*HEAD_SIZE
#define MALL (NB*LSEQ)   // 4096
#define KSPLIT 4

// ---------------- K1: seq_out partials = inputs @ Wp (K split in 4) --------
// grid (8, 64): x = nt(2) + 2*split(4), y = m-tile. 256 threads, 64x64 tile,
// micro 4x4 per thread, K-chunk 32, 8 chunks per split.
__global__ __launch_bounds__(256) void k1_gemm(const float* __restrict__ A,
                                               const float* __restrict__ Wp,
                                               float* __restrict__ Cp) {
    const int nt    = blockIdx.x & 1;
    const int split = blockIdx.x >> 1;
    const int m0 = blockIdx.y * 64;
    const int n0 = nt * 64;
    __shared__ float As[32][68];   // [k][m], pad 68 keeps float4 reads 16B-aligned
    __shared__ float Bs[32][64];   // [k][n]
    const int tid = threadIdx.x;
    const int tm = tid & 15;       // m quad
    const int tn = tid >> 4;       // n quad
    float acc[4][4] = {};
    for (int kc = 0; kc < 8; ++kc) {
        const int k0 = split*256 + kc*32;
        #pragma unroll
        for (int p = 0; p < 2; ++p) {
            int idx = tid + 256*p;          // 0..511
            int row = idx >> 3, kq = idx & 7;
            float4 a = *(const float4*)(A + (size_t)(m0+row)*HDIM + k0 + 4*kq);
            As[4*kq+0][row] = a.x;
            As[4*kq+1][row] = a.y;
            As[4*kq+2][row] = a.z;
            As[4*kq+3][row] = a.w;
        }
        #pragma unroll
        for (int p = 0; p < 2; ++p) {
            int idx = tid + 256*p;
            int r = idx >> 4, c = idx & 15;
            *(float4*)(&Bs[r][4*c]) = *(const float4*)(Wp + (size_t)(k0+r)*NKV + n0 + 4*c);
        }
        __syncthreads();
        #pragma unroll
        for (int kk = 0; kk < 32; ++kk) {
            float4 av = *(const float4*)(&As[kk][4*tm]);
            float4 bv = *(const float4*)(&Bs[kk][4*tn]);
            float aa[4] = {av.x, av.y, av.z, av.w};
            float bb[4] = {bv.x, bv.y, bv.z, bv.w};
            #pragma unroll
            for (int i = 0; i < 4; ++i)
                #pragma unroll
                for (int j = 0; j < 4; ++j)
                    acc[i][j] = fmaf(aa[i], bb[j], acc[i][j]);
        }
        __syncthreads();
    }
    float* outp = Cp + (size_t)split*MALL*NKV;
    #pragma unroll
    for (int i = 0; i < 4; ++i) {
        float4 v = make_float4(acc[i][0], acc[i][1], acc[i][2], acc[i][3]);
        *(float4*)(outp + (size_t)(m0 + 4*tm + i)*NKV + n0 + 4*tn) = v;
    }
}

// ---------------- K2: sum K-splits (+bp), RoPE, bias = seq@Wq/2 ------------
// grid 4096 blocks x 64 threads (1 wave per row).
__global__ __launch_bounds__(64) void k2_rope_bias(const float* __restrict__ Cp,
        const float* __restrict__ bp, const float* __restrict__ Wq,
        const float* __restrict__ bq, float* __restrict__ qwout,
        float* __restrict__ kwout, float* __restrict__ biasQ,
        float* __restrict__ biasK) {
    const int row = blockIdx.x;         // 0..4095 (b*L + l)
    const int b = row >> 11;
    const int l = row & (LSEQ - 1);
    const int t = threadIdx.x;          // 0..63 ; lane t owns dims (2t, 2t+1)
    float x0 = bp[2*t], x1 = bp[2*t+1];
    #pragma unroll
    for (int s = 0; s < KSPLIT; ++s) {
        const float* r = Cp + (size_t)s*MALL*NKV + (size_t)row*NKV;
        x0 += r[2*t];
        x1 += r[2*t+1];
    }
    // RoPE: lanes 0..31 -> q (dims 0..63), lanes 32..63 -> k (dims 64..127)
    const int p = t & 31;               // pair index within head
    float inv = exp2f(-0.41524101186098287f * (float)p);  // 10000^(-p/32)
    float ang = (float)l * inv;
    float sn = sinf(ang), cs = cosf(ang);
    float y0 = x0*cs - x1*sn;
    float y1 = x1*cs + x0*sn;
    float* dst = (t < 32) ? (qwout + (size_t)row*64) : (kwout + (size_t)row*64);
    dst[2*p]   = y0;
    dst[2*p+1] = y1;
    // bias: 24 dot-products of (pre-RoPE) row with Wq columns, wave-reduced
    float res = 0.f;
    for (int j = 0; j < 24; ++j) {
        float part = fmaf(x0, Wq[(2*t)*24 + j], x1 * Wq[(2*t+1)*24 + j]);
        #pragma unroll
        for (int off = 32; off > 0; off >>= 1)
            part += __shfl_xor(part, off);
        if (t == j) res = part;
    }
    if (t < 24) {
        float v = (res + bq[t]) * 0.5f;
        int h = t >> 1;
        float* bb = (t & 1) ? biasK : biasQ;
        bb[((size_t)b*12 + h)*LSEQ + l] = v;
    }
}

// ---------------- K3 v4: v2 structure, plain stores + lgkm-only barriers ---
// grid (512, 2): x = m-tile (4 rows), y = b. 256 threads.
// Thread: g = tid>>7 owns m rows {2g,2g+1} (q in 128 VGPRs), nl = tid&127.
// Loop 16 chunks of 128 n: stage kw chunk to LDS coalesced, dot from LDS,
// fan out 12 heads. A/B vs baseline: (T-A) PLAIN dword stores (L2 aggregates
// writebacks; NT bypassed L2 and hot-spotted HBM channels at 16MB stride),
// (T-B) barriers are lgkmcnt-only raw s_barrier (no vmcnt(0) store drain;
// barriers only protect LDS). Everything else bit-identical to baseline.
// Barrier protocol: both barriers executed unconditionally by all 256
// threads in a uniform 16-iter loop -> no divergence hang possible.
__global__ __launch_bounds__(256, 2) void k3_scores(const float* __restrict__ qw,
        const float* __restrict__ kwv, const float* __restrict__ biasQ,
        const float* __restrict__ biasK, const int* __restrict__ mask,
        float* __restrict__ out) {
    const int m0 = blockIdx.x * 4;
    const int b  = blockIdx.y;
    const int tid = threadIdx.x;
    const int nl = tid & 127;
    const int g  = tid >> 7;            // 0/1 -> m rows 2g, 2g+1
    __shared__ float kws[128 * 68];     // pad 68: word off 4*(n+j) mod 32 -> even banks

    const size_t rowbase = (size_t)b * LSEQ;
    const int mA = m0 + 2*g, mB = mA + 1;

    float4 q0[16], q1[16];
    {
        const float4* qp0 = (const float4*)(qw + (rowbase + mA)*64);
        const float4* qp1 = (const float4*)(qw + (rowbase + mB)*64);
        #pragma unroll
        for (int j = 0; j < 16; ++j) { q0[j] = qp0[j]; q1[j] = qp1[j]; }
    }
    float bq0[12], bq1[12];
    #pragma unroll
    for (int h = 0; h < 12; ++h) {
        const float* bqp = biasQ + ((size_t)b*12 + h)*LSEQ;
        bq0[h] = bqp[mA];
        bq1[h] = bqp[mB];
    }
    const bool okmA = mask[rowbase + mA] != 0;
    const bool okmB = mask[rowbase + mB] != 0;
    const size_t outbase = (size_t)b * 12 * LSEQ * LSEQ;

    for (int c = 0; c < 16; ++c) {
        const int nbase = c * 128;
        // barrier 1: all waves done READING kws from previous chunk.
        // lgkmcnt-only: LDS reads are in-register before here (compiler deps);
        // do NOT drain vmcnt (outstanding global stores keep flowing).
        asm volatile("s_waitcnt lgkmcnt(0)" ::: "memory");
        __builtin_amdgcn_s_barrier();
        asm volatile("" ::: "memory");
        #pragma unroll
        for (int p = 0; p < 8; ++p) {
            int f4 = tid + 256*p;        // 0..2047 float4-chunks
            int r = f4 >> 4, q16 = f4 & 15;
            float4 v = *(const float4*)(kwv + (rowbase + nbase + r)*64 + 4*q16);
            *(float4*)(&kws[r*68 + 4*q16]) = v;
        }
        // barrier 2: staging ds_writes visible to all waves.
        asm volatile("s_waitcnt lgkmcnt(0)" ::: "memory");
        __builtin_amdgcn_s_barrier();
        asm volatile("" ::: "memory");

        const int n = nbase + nl;
        float acc0 = 0.f, acc1 = 0.f;
        const float4* kr = (const float4*)(&kws[nl * 68]);  // 272B stride: 16B aligned
        #pragma unroll
        for (int j = 0; j < 16; ++j) {
            float4 kv = kr[j];
            acc0 = fmaf(q0[j].x, kv.x, acc0);
            acc0 = fmaf(q0[j].y, kv.y, acc0);
            acc0 = fmaf(q0[j].z, kv.z, acc0);
            acc0 = fmaf(q0[j].w, kv.w, acc0);
            acc1 = fmaf(q1[j].x, kv.x, acc1);
            acc1 = fmaf(q1[j].y, kv.y, acc1);
            acc1 = fmaf(q1[j].z, kv.z, acc1);
            acc1 = fmaf(q1[j].w, kv.w, acc1);
        }
        acc0 *= 0.125f;                  // / sqrt(64)
        acc1 *= 0.125f;

        const bool okn = mask[rowbase + n] != 0;
        const float penA = (mA > n) ? 1e12f : 0.f;
        const float penB = (mB > n) ? 1e12f : 0.f;
        const bool okA = okmA && okn;
        const bool okB = okmB && okn;
        size_t offA = outbase + (size_t)mA * LSEQ + n;
        const float* bkp = biasK + (size_t)b*12*LSEQ + n;
        #pragma unroll
        for (int h = 0; h < 12; ++h) {
            float bk = bkp[(size_t)h * LSEQ];
            float v0 = acc0 + bq0[h] + bk;
            v0 = okA ? v0 : -INFINITY;
            v0 -= penA;
            float v1 = acc1 + bq1[h] + bk;
            v1 = okB ? v1 : -INFINITY;
            v1 -= penB;
            out[offA + (size_t)h*LSEQ*LSEQ]        = v0;   // plain: L2-aggregated
            out[offA + LSEQ + (size_t)h*LSEQ*LSEQ] = v1;
        }
    }
}

extern "C" void kernel_launch(void* const* d_in, const int* in_sizes, int n_in,
                              void* d_out, int out_size, void* d_ws, size_t ws_size,
                              hipStream_t stream) {
    const float* inputs = (const float*)d_in[0];   // (2,2048,1024)
    const int*   mask   = (const int*)  d_in[1];   // (2,2048)
    const float* Wp     = (const float*)d_in[2];   // (1024,128)
    const float* bp     = (const float*)d_in[3];   // (128,)
    const float* Wq     = (const float*)d_in[4];   // (128,24)
    const float* bq     = (const float*)d_in[5];   // (24,)
    float* out = (float*)d_out;                    // (2,12,2048,2048)

    float* Cp  = (float*)d_ws;                     // KSPLIT * 4096 * 128
    float* qwb = Cp  + (size_t)KSPLIT*MALL*NKV;    // 4096 * 64
    float* kwb = qwb + (size_t)MALL*64;            // 4096 * 64
    float* bQ  = kwb + (size_t)MALL*64;            // 2*12*2048
    float* bK  = bQ  + (size_t)NB*12*LSEQ;         // 2*12*2048

    k1_gemm     <<<dim3(8, 64),   256, 0, stream>>>(inputs, Wp, Cp);
    k2_rope_bias<<<dim3(MALL),     64, 0, stream>>>(Cp, bp, Wq, bq, qwb, kwb, bQ, bK);
    k3_scores   <<<dim3(512, 2), 256, 0, stream>>>(qwb, kwb, bQ, bK, mask, out);
}